// Round 1
// 456.203 us; speedup vs baseline: 1.2206x; 1.2206x over previous
//
#include <hip/hip_runtime.h>
#include <hip/hip_bf16.h>
#include <math.h>

#define IN_CH 128
#define HID 64
#define OUT_CH 40

typedef const __hip_bfloat16* bf16p;
typedef __attribute__((ext_vector_type(8))) short bf16x8;
typedef __attribute__((ext_vector_type(4))) float f32x4;

// ---- flag detection: flags[0]=1 if float tensors are f32, flags[1]=1 if indices are int64
//      flags[2] = gemm1-mfma verification failure flag (0 = ok)
__global__ void k_detect(const void* x, const void* ei, int* flags) {
    __shared__ int s_f32, s_hi;
    if (threadIdx.x == 0) { s_f32 = 0; s_hi = 0; }
    __syncthreads();
    const __hip_bfloat16* xb = (const __hip_bfloat16*)x;
    const int* ii = (const int*)ei;
    int lf = 0, lh = 0;
    for (int i = threadIdx.x; i < 4096; i += blockDim.x) {
        float f = __bfloat162float(xb[i]);
        if (!(fabsf(f) <= 1e4f)) lf = 1;       // huge/NaN -> buffer is really f32
        lh |= ii[2 * i + 1];                    // int64 high words are all zero
    }
    if (lf) atomicOr(&s_f32, 1);
    if (lh) atomicOr(&s_hi, 1);
    __syncthreads();
    if (threadIdx.x == 0) {
        flags[0] = s_f32 ? 1 : 0;
        flags[1] = (s_hi == 0) ? 1 : 0;
        flags[2] = 0;
    }
}

// ---- convert weights/biases to f32: wf = [W1f 8192 | b1f 64 | W2f 2560 | b2f 40]
__global__ void k_convw(const void* W1, const void* b1, const void* W2, const void* b2,
                        const int* flags, float* wf) {
    int i = blockIdx.x * blockDim.x + threadIdx.x;
    if (i >= 10856) return;
    const void* src; int off;
    if (i < 8192)       { src = W1; off = i; }
    else if (i < 8256)  { src = b1; off = i - 8192; }
    else if (i < 10816) { src = W2; off = i - 8256; }
    else                { src = b2; off = i - 10816; }
    float v;
    if (flags[0]) v = ((const float*)src)[off];
    else          v = __bfloat162float(((bf16p)src)[off]);
    wf[i] = v;
}

// ---- in-degree histogram over col (int)
__global__ void k_deg(const int* ei, const int* flags, int* deg, int E) {
    int e = blockIdx.x * blockDim.x + threadIdx.x;
    if (e >= E) return;
    int c;
    if (flags[1]) c = ei[2 * (E + e)];
    else          c = ei[E + e];
    atomicAdd(&deg[c], 1);
}

__global__ void k_dinv(const int* deg, float* dinv, int N) {
    int i = blockIdx.x * blockDim.x + threadIdx.x;
    if (i >= N) return;
    dinv[i] = rsqrtf((float)deg[i] + 1.0f);   // +1 = self-loop
}

// ---- exclusive scan over deg -> rowstart (3 kernels)
__global__ void k_blocksum(const int* deg, int* bsum, int N) {
    __shared__ int s[256];
    int i = blockIdx.x * 256 + threadIdx.x;
    s[threadIdx.x] = (i < N) ? deg[i] : 0;
    __syncthreads();
    for (int off = 128; off > 0; off >>= 1) {
        if (threadIdx.x < off) s[threadIdx.x] += s[threadIdx.x + off];
        __syncthreads();
    }
    if (threadIdx.x == 0) bsum[blockIdx.x] = s[0];
}

__global__ void k_scanbsum(int* bsum, int NB) {
    __shared__ int s[1024];
    __shared__ int carry_s;
    if (threadIdx.x == 0) carry_s = 0;
    __syncthreads();
    for (int base = 0; base < NB; base += 1024) {
        int i = base + threadIdx.x;
        int v = (i < NB) ? bsum[i] : 0;
        s[threadIdx.x] = v;
        __syncthreads();
        for (int off = 1; off < 1024; off <<= 1) {
            int t = (threadIdx.x >= off) ? s[threadIdx.x - off] : 0;
            __syncthreads();
            s[threadIdx.x] += t;
            __syncthreads();
        }
        int total = s[1023];
        int excl = s[threadIdx.x] - v + carry_s;
        if (i < NB) bsum[i] = excl;
        __syncthreads();
        if (threadIdx.x == 0) carry_s += total;
        __syncthreads();
    }
}

// rowstart + pre-seeded fill (saves a random load per edge in k_scatter)
__global__ void k_scanfinal(const int* deg, const int* boff, int* rowstart, int* fill, int N) {
    __shared__ int s[256];
    int i = blockIdx.x * 256 + threadIdx.x;
    int v = (i < N) ? deg[i] : 0;
    s[threadIdx.x] = v;
    __syncthreads();
    for (int off = 1; off < 256; off <<= 1) {
        int t = (threadIdx.x >= off) ? s[threadIdx.x - off] : 0;
        __syncthreads();
        s[threadIdx.x] += t;
        __syncthreads();
    }
    if (i < N) {
        int rs = boff[blockIdx.x] + s[threadIdx.x] - v;
        rowstart[i] = rs;
        fill[i] = rs;
    }
    if (i == N - 1) rowstart[N] = boff[blockIdx.x] + s[threadIdx.x];
}

// ---- bucket-scatter edges into CSR, XCD-sliced; r loaded ONLY for passing edges
__global__ void k_scatter(const int* ei, const int* flags, int* fill, int* erow,
                          int E, int N) {
    int slice = blockIdx.x & 7;
    int nlo = (int)(((long)N * slice) >> 3);
    int nhi = (int)(((long)N * (slice + 1)) >> 3);
    int nblk = gridDim.x >> 3;
    int bid = blockIdx.x >> 3;
    int i64 = flags[1];
    for (int e = bid * 256 + threadIdx.x; e < E; e += nblk * 256) {
        int c;
        if (i64) c = ei[2 * (E + e)];
        else     c = ei[E + e];
        if (c >= nlo && c < nhi) {
            int r;
            if (i64) r = ei[2 * e];
            else     r = ei[e];
            int pos = atomicAdd(&fill[c], 1);
            erow[pos] = r;
        }
    }
}

// ---- GEMM1 via MFMA: h1b[n][c] = bf16(sum_k x[n][k]*W1[k][c])
//      One wave per 16-node tile. W1^T staged in LDS as bf16 (16 KB), held as
//      16 B-fragments in registers. A-fragments loaded straight from global x.
//      Fragment layouts (measured, m89/m91):
//        A: lane l, elem j -> A[l&15][(l>>4)*8 + j]
//        B: lane l, elem j -> B[(l>>4)*8 + j][l&15]
//        C: lane l, reg  q -> C[(l>>4)*4 + q][l&15]
__global__ __launch_bounds__(256) void k_gemm1_mfma(const void* x, const float* W1f,
        __hip_bfloat16* h1b, const int* flags, int N) {
    __shared__ __align__(16) unsigned short wT[HID][IN_CH];   // W1^T, bf16 bits, 16 KB
    for (int i = threadIdx.x; i < IN_CH * HID; i += 256) {
        int k = i >> 6, c = i & 63;
        __hip_bfloat16 b = __float2bfloat16(W1f[i]);
        wT[c][k] = *reinterpret_cast<unsigned short*>(&b);
    }
    __syncthreads();

    const int isF32 = flags[0];
    const int lane = threadIdx.x & 63;
    const int wid  = threadIdx.x >> 6;
    const int r = lane & 15;     // A row / B col / C col within tile
    const int g = lane >> 4;     // k-group

    // B fragments: bfr[nt][ks] covers cols [nt*16,nt*16+16) x k [ks*32, ks*32+32)
    bf16x8 bfr[4][4];
    #pragma unroll
    for (int nt = 0; nt < 4; ++nt)
        #pragma unroll
        for (int ks = 0; ks < 4; ++ks)
            bfr[nt][ks] = *(const bf16x8*)&wT[nt * 16 + r][ks * 32 + g * 8];

    const int tiles = (N + 15) >> 4;
    for (int t = blockIdx.x * 4 + wid; t < tiles; t += gridDim.x * 4) {
        const int row0 = t * 16;
        int arow = row0 + r; if (arow >= N) arow = N - 1;   // clamp (stores guarded)
        bf16x8 afr[4];
        if (!isF32) {
            const unsigned short* xr = (const unsigned short*)x + (size_t)arow * IN_CH;
            #pragma unroll
            for (int ks = 0; ks < 4; ++ks)
                afr[ks] = *(const bf16x8*)&xr[ks * 32 + g * 8];
        } else {
            const float* xr = (const float*)x + (size_t)arow * IN_CH;
            #pragma unroll
            for (int ks = 0; ks < 4; ++ks) {
                #pragma unroll
                for (int j = 0; j < 8; ++j) {
                    __hip_bfloat16 b = __float2bfloat16(xr[ks * 32 + g * 8 + j]);
                    afr[ks][j] = *reinterpret_cast<short*>(&b);
                }
            }
        }
        f32x4 acc[4] = {};
        #pragma unroll
        for (int ks = 0; ks < 4; ++ks)
            #pragma unroll
            for (int nt = 0; nt < 4; ++nt)
                acc[nt] = __builtin_amdgcn_mfma_f32_16x16x32_bf16(afr[ks], bfr[nt][ks],
                                                                  acc[nt], 0, 0, 0);
        #pragma unroll
        for (int nt = 0; nt < 4; ++nt) {
            #pragma unroll
            for (int q = 0; q < 4; ++q) {
                int rr = row0 + g * 4 + q;
                if (rr < N)
                    h1b[(size_t)rr * HID + nt * 16 + r] = __float2bfloat16(acc[nt][q]);
            }
        }
    }
}

// ---- sampled verification of the MFMA gemm1 (4096 (node,ch) pairs).
//      Wrong fragment layout => O(1) errors on most samples; bf16 noise << 0.25.
__global__ void k_gemm1_check(const void* x, const float* W1f, const __hip_bfloat16* h1b,
                              int* flags, int N) {
    int idx = blockIdx.x * blockDim.x + threadIdx.x;
    int ni = idx >> 6, c = idx & 63;
    int n = (int)(((long)ni * 1567) % N);
    float ref = 0.f;
    if (flags[0]) {
        const float* xr = (const float*)x + (size_t)n * IN_CH;
        for (int k = 0; k < IN_CH; ++k) ref += xr[k] * W1f[k * HID + c];
    } else {
        bf16p xr = (bf16p)x + (size_t)n * IN_CH;
        for (int k = 0; k < IN_CH; ++k) ref += __bfloat162float(xr[k]) * W1f[k * HID + c];
    }
    float got = __bfloat162float(h1b[(size_t)n * HID + c]);
    if (fabsf(got - ref) > 0.25f + 0.05f * fabsf(ref)) atomicOr(&flags[2], 1);
}

// ---- fallback GEMM1 (previous proven kernel); runs only if verification failed
__global__ __launch_bounds__(256) void k_gemm1_fb(const void* x, const float* W1f,
                                                  __hip_bfloat16* h1b, const int* flags, int N) {
    if (flags[2] == 0) return;   // MFMA result verified ok -> nothing to do
    __shared__ float w[IN_CH * HID];
    for (int i = threadIdx.x; i < IN_CH * HID; i += 256) w[i] = W1f[i];
    __syncthreads();
    const int isF32 = flags[0];
    const int c = threadIdx.x & 63;
    const int q = threadIdx.x >> 6;
    for (int n = blockIdx.x * 4 + q; n < N; n += gridDim.x * 4) {
        float acc = 0.f;
        if (isF32) {
            const float* xr = (const float*)x + (size_t)n * IN_CH;
            #pragma unroll 8
            for (int k = 0; k < IN_CH; ++k) acc += xr[k] * w[k * HID + c];
        } else {
            bf16p xr = (bf16p)x + (size_t)n * IN_CH;
            #pragma unroll 8
            for (int k = 0; k < IN_CH; ++k) acc += __bfloat162float(xr[k]) * w[k * HID + c];
        }
        h1b[(size_t)n * HID + c] = __float2bfloat16(acc);
    }
}

// ---- Fused aggregation1 (+self-loop+bias+ReLU) AND GEMM2: one wave per node.
//      Gather bf16 h1 (128 B/edge), g via LDS round-trip, h2 stored as bf16 40ch.
__global__ __launch_bounds__(256) void k_agg1gemm2(const int* rowstart, const int* erow,
        const __hip_bfloat16* h1b, const float* dinv, const float* b1f, const float* w2f,
        __hip_bfloat16* h2b, int N) {
    __shared__ float w2[HID * OUT_CH];   // 2560 floats
    __shared__ float sg[256];            // per-wave g slices
    for (int i = threadIdx.x; i < HID * OUT_CH; i += 256) w2[i] = w2f[i];
    __syncthreads();

    int w = (blockIdx.x * 256 + threadIdx.x) >> 6;
    int c = threadIdx.x & 63;
    bool act = (w < N);
    float g = 0.f;
    if (act) {
        int s0 = __builtin_amdgcn_readfirstlane(rowstart[w]);
        int s1 = __builtin_amdgcn_readfirstlane(rowstart[w + 1]);
        float d = dinv[w];
        float acc = __bfloat162float(h1b[(size_t)w * HID + c]) * d * d + b1f[c];
        int i = s0;
        for (; i + 1 < s1; i += 2) {
            int r0 = erow[i];     int r1 = erow[i + 1];
            float n0 = dinv[r0] * d;
            float n1 = dinv[r1] * d;
            float v0 = __bfloat162float(h1b[(size_t)r0 * HID + c]);
            float v1 = __bfloat162float(h1b[(size_t)r1 * HID + c]);
            acc += v0 * n0 + v1 * n1;
        }
        if (i < s1) {
            int r = erow[i];
            acc += __bfloat162float(h1b[(size_t)r * HID + c]) * (dinv[r] * d);
        }
        g = fmaxf(acc, 0.f);
    }
    sg[threadIdx.x] = g;
    __syncthreads();
    if (act && c < OUT_CH) {
        const float* gs = sg + (threadIdx.x & 192);   // this wave's 64-slice
        float acc2 = 0.f;
        #pragma unroll
        for (int k = 0; k < HID; ++k) acc2 += gs[k] * w2[k * OUT_CH + c];
        h2b[(size_t)w * OUT_CH + c] = __float2bfloat16(acc2);
    }
}

// ---- Aggregation 2 (CSR) on bf16 h2 (40ch, 80 B/edge gathers); +b2 -> f32 d_out
__global__ __launch_bounds__(256) void k_agg2(const int* rowstart, const int* erow,
        const __hip_bfloat16* h2b, const float* dinv, const float* b2f,
        float* out, int N) {
    int w = (blockIdx.x * 256 + threadIdx.x) >> 6;
    int c = threadIdx.x & 63;
    if (w >= N) return;
    int s0 = __builtin_amdgcn_readfirstlane(rowstart[w]);
    int s1 = __builtin_amdgcn_readfirstlane(rowstart[w + 1]);
    float d = dinv[w];
    float acc = 0.f;
    if (c < OUT_CH) acc = __bfloat162float(h2b[(size_t)w * OUT_CH + c]) * d * d + b2f[c];
    int i = s0;
    for (; i + 1 < s1; i += 2) {
        int r0 = erow[i];     int r1 = erow[i + 1];
        float n0 = dinv[r0] * d;
        float n1 = dinv[r1] * d;
        if (c < OUT_CH) {
            float v0 = __bfloat162float(h2b[(size_t)r0 * OUT_CH + c]);
            float v1 = __bfloat162float(h2b[(size_t)r1 * OUT_CH + c]);
            acc += v0 * n0 + v1 * n1;
        }
    }
    if (i < s1 && c < OUT_CH) {
        int r = erow[i];
        acc += __bfloat162float(h2b[(size_t)r * OUT_CH + c]) * (dinv[r] * d);
    }
    if (c < OUT_CH) out[(size_t)w * OUT_CH + c] = acc;
}

extern "C" void kernel_launch(void* const* d_in, const int* in_sizes, int n_in,
                              void* d_out, int out_size, void* d_ws, size_t ws_size,
                              hipStream_t stream) {
    const void* x  = d_in[0];
    const void* ei = d_in[1];
    const void* W1 = d_in[2];
    const void* b1 = d_in[3];
    const void* W2 = d_in[4];
    const void* b2 = d_in[5];
    const int N = in_sizes[0] / IN_CH;   // 100000
    const int E = in_sizes[1] / 2;       // 1600000
    const int* eii = (const int*)ei;
    const int NB = (N + 255) / 256;

    // ---- workspace layout (4-byte units). Peak ~29 MiB.
    float* ws = (float*)d_ws;
    size_t off = 16;
    int*   flags    = (int*)ws;
    int*   deg      = (int*)ws + off;            off += N;
    int*   fill     = (int*)ws + off;            off += N;
    float* dinv     = ws + off;                  off += N;
    float* wf       = ws + off;                  off += 10880;
    int*   bsum     = (int*)ws + off;            off += NB + 16;
    int*   rowstart = (int*)ws + off;            off += N + 1;
    off = (off + 255) & ~(size_t)255;
    int*   erow     = (int*)ws + off;            off += E;
    __hip_bfloat16* h1b = (__hip_bfloat16*)(ws + off);     off += (size_t)N * HID / 2;
    __hip_bfloat16* h2b = (__hip_bfloat16*)(ws + off);     off += (size_t)N * OUT_CH / 2;

    hipMemsetAsync(deg, 0, (size_t)N * sizeof(int), stream);  // deg only; fill pre-seeded

    k_detect<<<1, 256, 0, stream>>>(x, ei, flags);
    k_convw<<<(10856 + 255) / 256, 256, 0, stream>>>(W1, b1, W2, b2, flags, wf);
    k_deg<<<(E + 255) / 256, 256, 0, stream>>>(eii, flags, deg, E);
    k_dinv<<<(N + 255) / 256, 256, 0, stream>>>(deg, dinv, N);

    k_blocksum<<<NB, 256, 0, stream>>>(deg, bsum, N);
    k_scanbsum<<<1, 1024, 0, stream>>>(bsum, NB);
    k_scanfinal<<<NB, 256, 0, stream>>>(deg, bsum, rowstart, fill, N);
    k_scatter<<<4096, 256, 0, stream>>>(eii, flags, fill, erow, E, N);

    // GEMM1: MFMA kernel (2 tiles/wave), sampled check, guarded fallback
    int tiles = (N + 15) / 16;
    int g1 = (tiles + 7) / 8;           // 4 waves/block, 2 tiles/wave
    k_gemm1_mfma<<<g1, 256, 0, stream>>>(x, wf, h1b, flags, N);
    k_gemm1_check<<<16, 256, 0, stream>>>(x, wf, h1b, flags, N);
    k_gemm1_fb<<<2048, 256, 0, stream>>>(x, wf, h1b, flags, N);

    int nodeBlocks = (N * 64 + 255) / 256;   // 25000
    k_agg1gemm2<<<nodeBlocks, 256, 0, stream>>>(rowstart, erow, h1b, dinv,
                                                wf + 8192, wf + 8256, h2b, N);
    k_agg2<<<nodeBlocks, 256, 0, stream>>>(rowstart, erow, h2b, dinv,
                                           wf + 10816, (float*)d_out, N);
}

// Round 2
// 425.120 us; speedup vs baseline: 1.3099x; 1.0731x over previous
//
#include <hip/hip_runtime.h>
#include <hip/hip_bf16.h>
#include <math.h>

#define IN_CH 128
#define HID 64
#define OUT_CH 40

typedef const __hip_bfloat16* bf16p;
typedef __attribute__((ext_vector_type(8))) short bf16x8;
typedef __attribute__((ext_vector_type(4))) short bf16x4;
typedef __attribute__((ext_vector_type(4))) float f32x4;

// bf16 -> f32 is exact: shift into the high half
__device__ __forceinline__ f32x4 cvt4(bf16x4 v) {
    f32x4 o;
    #pragma unroll
    for (int j = 0; j < 4; ++j) {
        unsigned int bits = ((unsigned int)(unsigned short)v[j]) << 16;
        o[j] = __uint_as_float(bits);
    }
    return o;
}

// ---- flag detection: flags[0]=1 if float tensors are f32, flags[1]=1 if indices are int64
__global__ void k_detect(const void* x, const void* ei, int* flags) {
    __shared__ int s_f32, s_hi;
    if (threadIdx.x == 0) { s_f32 = 0; s_hi = 0; }
    __syncthreads();
    const __hip_bfloat16* xb = (const __hip_bfloat16*)x;
    const int* ii = (const int*)ei;
    int lf = 0, lh = 0;
    for (int i = threadIdx.x; i < 4096; i += blockDim.x) {
        float f = __bfloat162float(xb[i]);
        if (!(fabsf(f) <= 1e4f)) lf = 1;       // huge/NaN -> buffer is really f32
        lh |= ii[2 * i + 1];                    // int64 high words are all zero
    }
    if (lf) atomicOr(&s_f32, 1);
    if (lh) atomicOr(&s_hi, 1);
    __syncthreads();
    if (threadIdx.x == 0) {
        flags[0] = s_f32 ? 1 : 0;
        flags[1] = (s_hi == 0) ? 1 : 0;
        flags[2] = 0;
    }
}

// ---- convert weights/biases to f32: wf = [W1f 8192 | b1f 64 | W2f 2560 | b2f 40]
__global__ void k_convw(const void* W1, const void* b1, const void* W2, const void* b2,
                        const int* flags, float* wf) {
    int i = blockIdx.x * blockDim.x + threadIdx.x;
    if (i >= 10856) return;
    const void* src; int off;
    if (i < 8192)       { src = W1; off = i; }
    else if (i < 8256)  { src = b1; off = i - 8192; }
    else if (i < 10816) { src = W2; off = i - 8256; }
    else                { src = b2; off = i - 10816; }
    float v;
    if (flags[0]) v = ((const float*)src)[off];
    else          v = __bfloat162float(((bf16p)src)[off]);
    wf[i] = v;
}

// ---- in-degree histogram over col (int)
__global__ void k_deg(const int* ei, const int* flags, int* deg, int E) {
    int e = blockIdx.x * blockDim.x + threadIdx.x;
    if (e >= E) return;
    int c;
    if (flags[1]) c = ei[2 * (E + e)];
    else          c = ei[E + e];
    atomicAdd(&deg[c], 1);
}

__global__ void k_dinv(const int* deg, float* dinv, int N) {
    int i = blockIdx.x * blockDim.x + threadIdx.x;
    if (i >= N) return;
    dinv[i] = rsqrtf((float)deg[i] + 1.0f);   // +1 = self-loop
}

// ---- exclusive scan over deg -> rowstart (3 kernels)
__global__ void k_blocksum(const int* deg, int* bsum, int N) {
    __shared__ int s[256];
    int i = blockIdx.x * 256 + threadIdx.x;
    s[threadIdx.x] = (i < N) ? deg[i] : 0;
    __syncthreads();
    for (int off = 128; off > 0; off >>= 1) {
        if (threadIdx.x < off) s[threadIdx.x] += s[threadIdx.x + off];
        __syncthreads();
    }
    if (threadIdx.x == 0) bsum[blockIdx.x] = s[0];
}

__global__ void k_scanbsum(int* bsum, int NB) {
    __shared__ int s[1024];
    __shared__ int carry_s;
    if (threadIdx.x == 0) carry_s = 0;
    __syncthreads();
    for (int base = 0; base < NB; base += 1024) {
        int i = base + threadIdx.x;
        int v = (i < NB) ? bsum[i] : 0;
        s[threadIdx.x] = v;
        __syncthreads();
        for (int off = 1; off < 1024; off <<= 1) {
            int t = (threadIdx.x >= off) ? s[threadIdx.x - off] : 0;
            __syncthreads();
            s[threadIdx.x] += t;
            __syncthreads();
        }
        int total = s[1023];
        int excl = s[threadIdx.x] - v + carry_s;
        if (i < NB) bsum[i] = excl;
        __syncthreads();
        if (threadIdx.x == 0) carry_s += total;
        __syncthreads();
    }
}

// rowstart + pre-seeded fill (saves a random load per edge in k_scatter)
__global__ void k_scanfinal(const int* deg, const int* boff, int* rowstart, int* fill, int N) {
    __shared__ int s[256];
    int i = blockIdx.x * 256 + threadIdx.x;
    int v = (i < N) ? deg[i] : 0;
    s[threadIdx.x] = v;
    __syncthreads();
    for (int off = 1; off < 256; off <<= 1) {
        int t = (threadIdx.x >= off) ? s[threadIdx.x - off] : 0;
        __syncthreads();
        s[threadIdx.x] += t;
        __syncthreads();
    }
    if (i < N) {
        int rs = boff[blockIdx.x] + s[threadIdx.x] - v;
        rowstart[i] = rs;
        fill[i] = rs;
    }
    if (i == N - 1) rowstart[N] = boff[blockIdx.x] + s[threadIdx.x];
}

// ---- bucket-scatter edges into CSR, XCD-sliced; r loaded ONLY for passing edges
__global__ void k_scatter(const int* ei, const int* flags, int* fill, int* erow,
                          int E, int N) {
    int slice = blockIdx.x & 7;
    int nlo = (int)(((long)N * slice) >> 3);
    int nhi = (int)(((long)N * (slice + 1)) >> 3);
    int nblk = gridDim.x >> 3;
    int bid = blockIdx.x >> 3;
    int i64 = flags[1];
    for (int e = bid * 256 + threadIdx.x; e < E; e += nblk * 256) {
        int c;
        if (i64) c = ei[2 * (E + e)];
        else     c = ei[E + e];
        if (c >= nlo && c < nhi) {
            int r;
            if (i64) r = ei[2 * e];
            else     r = ei[e];
            int pos = atomicAdd(&fill[c], 1);
            erow[pos] = r;
        }
    }
}

// ---- GEMM1 via MFMA (HW-verified in R0): h1b[n][c] = bf16(sum_k x[n][k]*W1[k][c])
//      One wave per 16-node tile; W1^T in LDS as bf16; A straight from global.
//      A: lane l, elem j -> A[l&15][(l>>4)*8 + j]
//      B: lane l, elem j -> B[(l>>4)*8 + j][l&15]
//      C: lane l, reg  q -> C[(l>>4)*4 + q][l&15]
__global__ __launch_bounds__(256) void k_gemm1_mfma(const void* x, const float* W1f,
        __hip_bfloat16* h1b, const int* flags, int N) {
    __shared__ __align__(16) unsigned short wT[HID][IN_CH];   // W1^T, bf16 bits, 16 KB
    for (int i = threadIdx.x; i < IN_CH * HID; i += 256) {
        int k = i >> 6, c = i & 63;
        __hip_bfloat16 b = __float2bfloat16(W1f[i]);
        wT[c][k] = *reinterpret_cast<unsigned short*>(&b);
    }
    __syncthreads();

    const int isF32 = flags[0];
    const int lane = threadIdx.x & 63;
    const int wid  = threadIdx.x >> 6;
    const int r = lane & 15;     // A row / B col / C col within tile
    const int g = lane >> 4;     // k-group

    bf16x8 bfr[4][4];
    #pragma unroll
    for (int nt = 0; nt < 4; ++nt)
        #pragma unroll
        for (int ks = 0; ks < 4; ++ks)
            bfr[nt][ks] = *(const bf16x8*)&wT[nt * 16 + r][ks * 32 + g * 8];

    const int tiles = (N + 15) >> 4;
    for (int t = blockIdx.x * 4 + wid; t < tiles; t += gridDim.x * 4) {
        const int row0 = t * 16;
        int arow = row0 + r; if (arow >= N) arow = N - 1;   // clamp (stores guarded)
        bf16x8 afr[4];
        if (!isF32) {
            const unsigned short* xr = (const unsigned short*)x + (size_t)arow * IN_CH;
            #pragma unroll
            for (int ks = 0; ks < 4; ++ks)
                afr[ks] = *(const bf16x8*)&xr[ks * 32 + g * 8];
        } else {
            const float* xr = (const float*)x + (size_t)arow * IN_CH;
            #pragma unroll
            for (int ks = 0; ks < 4; ++ks) {
                #pragma unroll
                for (int j = 0; j < 8; ++j) {
                    __hip_bfloat16 b = __float2bfloat16(xr[ks * 32 + g * 8 + j]);
                    afr[ks][j] = *reinterpret_cast<short*>(&b);
                }
            }
        }
        f32x4 acc[4] = {};
        #pragma unroll
        for (int ks = 0; ks < 4; ++ks)
            #pragma unroll
            for (int nt = 0; nt < 4; ++nt)
                acc[nt] = __builtin_amdgcn_mfma_f32_16x16x32_bf16(afr[ks], bfr[nt][ks],
                                                                  acc[nt], 0, 0, 0);
        #pragma unroll
        for (int nt = 0; nt < 4; ++nt) {
            #pragma unroll
            for (int q = 0; q < 4; ++q) {
                int rr = row0 + g * 4 + q;
                if (rr < N)
                    h1b[(size_t)rr * HID + nt * 16 + r] = __float2bfloat16(acc[nt][q]);
            }
        }
    }
}

// ---- Fused aggregation1 (+self-loop+bias+ReLU) AND GEMM2.
//      One wave/node; lane = (sub = edge subgroup 0..3, cq = channel quad 0..15).
//      Each VMEM instr gathers 4 edges x 64ch (8B/lane), unrolled x2 = 8 edges in
//      flight. Cross-sub reduce via shfl_xor. No block barrier on the sg round-trip
//      (within-wave LDS, lockstep). h2 written padded to 64 ch (one 128B line/row).
__global__ __launch_bounds__(256) void k_agg1gemm2(const int* rowstart, const int* erow,
        const __hip_bfloat16* h1b, const float* dinv, const float* b1f, const float* w2f,
        __hip_bfloat16* h2b, int N) {
    __shared__ float w2[HID * OUT_CH];            // 2560 floats
    __shared__ __align__(16) float sg[256];       // per-wave g slices
    for (int i = threadIdx.x; i < HID * OUT_CH; i += 256) w2[i] = w2f[i];
    __syncthreads();

    const int w = (blockIdx.x * 256 + threadIdx.x) >> 6;
    if (w >= N) return;
    const int lane = threadIdx.x & 63;
    const int sub = lane >> 4;
    const int cq  = lane & 15;

    int s0 = __builtin_amdgcn_readfirstlane(rowstart[w]);
    int s1 = __builtin_amdgcn_readfirstlane(rowstart[w + 1]);
    float d = dinv[w];
    bf16x4 sv = *(const bf16x4*)&h1b[(size_t)w * HID + cq * 4];   // self quad, early

    f32x4 acc = {0.f, 0.f, 0.f, 0.f};
    int i = s0 + sub;
    for (; i + 4 < s1; i += 8) {
        int r0 = erow[i];
        int r1 = erow[i + 4];
        float n0 = dinv[r0] * d;
        float n1 = dinv[r1] * d;
        f32x4 v0 = cvt4(*(const bf16x4*)&h1b[(size_t)r0 * HID + cq * 4]);
        f32x4 v1 = cvt4(*(const bf16x4*)&h1b[(size_t)r1 * HID + cq * 4]);
        #pragma unroll
        for (int j = 0; j < 4; ++j) {
            acc[j] = fmaf(v0[j], n0, acc[j]);
            acc[j] = fmaf(v1[j], n1, acc[j]);
        }
    }
    if (i < s1) {
        int r = erow[i];
        float n = dinv[r] * d;
        f32x4 v = cvt4(*(const bf16x4*)&h1b[(size_t)r * HID + cq * 4]);
        #pragma unroll
        for (int j = 0; j < 4; ++j) acc[j] = fmaf(v[j], n, acc[j]);
    }
    #pragma unroll
    for (int j = 0; j < 4; ++j) {
        acc[j] += __shfl_xor(acc[j], 16, 64);
        acc[j] += __shfl_xor(acc[j], 32, 64);
    }
    f32x4 b1q = *(const f32x4*)&b1f[cq * 4];
    f32x4 sf = cvt4(sv);
    f32x4 g;
    #pragma unroll
    for (int j = 0; j < 4; ++j) g[j] = fmaxf(fmaf(sf[j], d * d, acc[j]) + b1q[j], 0.f);
    if (lane < 16) *(f32x4*)&sg[(threadIdx.x & 192) + cq * 4] = g;
    __builtin_amdgcn_wave_barrier();   // within-wave LDS write->read: order only

    const float* gs = sg + (threadIdx.x & 192);
    const int c = lane;
    float acc2 = 0.f;
    if (c < OUT_CH) {
        #pragma unroll
        for (int k4 = 0; k4 < 16; ++k4) {
            f32x4 gq = *(const f32x4*)&gs[k4 * 4];
            acc2 = fmaf(gq[0], w2[(k4 * 4 + 0) * OUT_CH + c], acc2);
            acc2 = fmaf(gq[1], w2[(k4 * 4 + 1) * OUT_CH + c], acc2);
            acc2 = fmaf(gq[2], w2[(k4 * 4 + 2) * OUT_CH + c], acc2);
            acc2 = fmaf(gq[3], w2[(k4 * 4 + 3) * OUT_CH + c], acc2);
        }
    }
    h2b[(size_t)w * 64 + c] = __float2bfloat16(c < OUT_CH ? acc2 : 0.f);
}

// ---- Aggregation 2 (CSR) on padded bf16 h2 (64ch rows). Same quad-gather
//      structure; +b2 -> f32 d_out, written as f32x4 from lanes 0..9.
__global__ __launch_bounds__(256) void k_agg2(const int* rowstart, const int* erow,
        const __hip_bfloat16* h2b, const float* dinv, const float* b2f,
        float* out, int N) {
    const int w = (blockIdx.x * 256 + threadIdx.x) >> 6;
    if (w >= N) return;
    const int lane = threadIdx.x & 63;
    const int sub = lane >> 4;
    const int cq  = lane & 15;

    int s0 = __builtin_amdgcn_readfirstlane(rowstart[w]);
    int s1 = __builtin_amdgcn_readfirstlane(rowstart[w + 1]);
    float d = dinv[w];
    bf16x4 sv = *(const bf16x4*)&h2b[(size_t)w * 64 + cq * 4];

    f32x4 acc = {0.f, 0.f, 0.f, 0.f};
    int i = s0 + sub;
    for (; i + 4 < s1; i += 8) {
        int r0 = erow[i];
        int r1 = erow[i + 4];
        float n0 = dinv[r0] * d;
        float n1 = dinv[r1] * d;
        f32x4 v0 = cvt4(*(const bf16x4*)&h2b[(size_t)r0 * 64 + cq * 4]);
        f32x4 v1 = cvt4(*(const bf16x4*)&h2b[(size_t)r1 * 64 + cq * 4]);
        #pragma unroll
        for (int j = 0; j < 4; ++j) {
            acc[j] = fmaf(v0[j], n0, acc[j]);
            acc[j] = fmaf(v1[j], n1, acc[j]);
        }
    }
    if (i < s1) {
        int r = erow[i];
        float n = dinv[r] * d;
        f32x4 v = cvt4(*(const bf16x4*)&h2b[(size_t)r * 64 + cq * 4]);
        #pragma unroll
        for (int j = 0; j < 4; ++j) acc[j] = fmaf(v[j], n, acc[j]);
    }
    #pragma unroll
    for (int j = 0; j < 4; ++j) {
        acc[j] += __shfl_xor(acc[j], 16, 64);
        acc[j] += __shfl_xor(acc[j], 32, 64);
    }
    if (lane < 10) {   // lanes 0..9 => cq 0..9 cover the 40 output channels
        f32x4 sf = cvt4(sv);
        f32x4 b2q = *(const f32x4*)&b2f[cq * 4];
        f32x4 o;
        #pragma unroll
        for (int j = 0; j < 4; ++j) o[j] = fmaf(sf[j], d * d, acc[j]) + b2q[j];
        *(f32x4*)&out[(size_t)w * 40 + cq * 4] = o;
    }
}

extern "C" void kernel_launch(void* const* d_in, const int* in_sizes, int n_in,
                              void* d_out, int out_size, void* d_ws, size_t ws_size,
                              hipStream_t stream) {
    const void* x  = d_in[0];
    const void* ei = d_in[1];
    const void* W1 = d_in[2];
    const void* b1 = d_in[3];
    const void* W2 = d_in[4];
    const void* b2 = d_in[5];
    const int N = in_sizes[0] / IN_CH;   // 100000
    const int E = in_sizes[1] / 2;       // 1600000
    const int* eii = (const int*)ei;
    const int NB = (N + 255) / 256;

    // ---- workspace layout (4-byte units). Peak ~35 MiB.
    float* ws = (float*)d_ws;
    size_t off = 16;
    int*   flags    = (int*)ws;
    int*   deg      = (int*)ws + off;            off += N;
    int*   fill     = (int*)ws + off;            off += N;
    float* dinv     = ws + off;                  off += N;
    float* wf       = ws + off;                  off += 10880;
    int*   bsum     = (int*)ws + off;            off += NB + 16;
    int*   rowstart = (int*)ws + off;            off += N + 1;
    off = (off + 255) & ~(size_t)255;
    int*   erow     = (int*)ws + off;            off += E;
    __hip_bfloat16* h1b = (__hip_bfloat16*)(ws + off);     off += (size_t)N * HID / 2;
    __hip_bfloat16* h2b = (__hip_bfloat16*)(ws + off);     off += (size_t)N * 64 / 2;  // padded

    hipMemsetAsync(deg, 0, (size_t)N * sizeof(int), stream);  // deg only; fill pre-seeded

    k_detect<<<1, 256, 0, stream>>>(x, ei, flags);
    k_convw<<<(10856 + 255) / 256, 256, 0, stream>>>(W1, b1, W2, b2, flags, wf);
    k_deg<<<(E + 255) / 256, 256, 0, stream>>>(eii, flags, deg, E);
    k_dinv<<<(N + 255) / 256, 256, 0, stream>>>(deg, dinv, N);

    k_blocksum<<<NB, 256, 0, stream>>>(deg, bsum, N);
    k_scanbsum<<<1, 1024, 0, stream>>>(bsum, NB);
    k_scanfinal<<<NB, 256, 0, stream>>>(deg, bsum, rowstart, fill, N);
    k_scatter<<<4096, 256, 0, stream>>>(eii, flags, fill, erow, E, N);

    int tiles = (N + 15) / 16;
    int g1 = (tiles + 7) / 8;           // 4 waves/block, 2 tiles/wave
    k_gemm1_mfma<<<g1, 256, 0, stream>>>(x, wf, h1b, flags, N);

    int nodeBlocks = (N * 64 + 255) / 256;   // 25000
    k_agg1gemm2<<<nodeBlocks, 256, 0, stream>>>(rowstart, erow, h1b, dinv,
                                                wf + 8192, wf + 8256, h2b, N);
    k_agg2<<<nodeBlocks, 256, 0, stream>>>(rowstart, erow, h2b, dinv,
                                           wf + 10816, (float*)d_out, N);
}

// Round 3
// 368.423 us; speedup vs baseline: 1.5115x; 1.1539x over previous
//
#include <hip/hip_runtime.h>
#include <hip/hip_bf16.h>
#include <math.h>

#define IN_CH 128
#define HID 64
#define OUT_CH 40

typedef const __hip_bfloat16* bf16p;
typedef __attribute__((ext_vector_type(8))) short bf16x8;
typedef __attribute__((ext_vector_type(4))) short bf16x4;
typedef __attribute__((ext_vector_type(4))) float f32x4;

// bf16 -> f32 is exact: shift into the high half
__device__ __forceinline__ f32x4 cvt4(bf16x4 v) {
    f32x4 o;
    #pragma unroll
    for (int j = 0; j < 4; ++j) {
        unsigned int bits = ((unsigned int)(unsigned short)v[j]) << 16;
        o[j] = __uint_as_float(bits);
    }
    return o;
}

__device__ __forceinline__ bf16x4 pack4(f32x4 v) {
    bf16x4 o;
    #pragma unroll
    for (int j = 0; j < 4; ++j) {
        __hip_bfloat16 b = __float2bfloat16(v[j]);
        o[j] = *reinterpret_cast<short*>(&b);
    }
    return o;
}

// ---- flag detection: flags[0]=1 if float tensors are f32, flags[1]=1 if indices are int64
__global__ void k_detect(const void* x, const void* ei, int* flags) {
    __shared__ int s_f32, s_hi;
    if (threadIdx.x == 0) { s_f32 = 0; s_hi = 0; }
    __syncthreads();
    const __hip_bfloat16* xb = (const __hip_bfloat16*)x;
    const int* ii = (const int*)ei;
    int lf = 0, lh = 0;
    for (int i = threadIdx.x; i < 4096; i += blockDim.x) {
        float f = __bfloat162float(xb[i]);
        if (!(fabsf(f) <= 1e4f)) lf = 1;       // huge/NaN -> buffer is really f32
        lh |= ii[2 * i + 1];                    // int64 high words are all zero
    }
    if (lf) atomicOr(&s_f32, 1);
    if (lh) atomicOr(&s_hi, 1);
    __syncthreads();
    if (threadIdx.x == 0) {
        flags[0] = s_f32 ? 1 : 0;
        flags[1] = (s_hi == 0) ? 1 : 0;
        flags[2] = 0;
    }
}

// ---- convert weights/biases to f32: wf = [W1f 8192 | b1f 64 | W2f 2560 | b2f 40]
__global__ void k_convw(const void* W1, const void* b1, const void* W2, const void* b2,
                        const int* flags, float* wf) {
    int i = blockIdx.x * blockDim.x + threadIdx.x;
    if (i >= 10856) return;
    const void* src; int off;
    if (i < 8192)       { src = W1; off = i; }
    else if (i < 8256)  { src = b1; off = i - 8192; }
    else if (i < 10816) { src = W2; off = i - 8256; }
    else                { src = b2; off = i - 10816; }
    float v;
    if (flags[0]) v = ((const float*)src)[off];
    else          v = __bfloat162float(((bf16p)src)[off]);
    wf[i] = v;
}

// ---- in-degree histogram over col (int)
__global__ void k_deg(const int* ei, const int* flags, int* deg, int E) {
    int e = blockIdx.x * blockDim.x + threadIdx.x;
    if (e >= E) return;
    int c;
    if (flags[1]) c = ei[2 * (E + e)];
    else          c = ei[E + e];
    atomicAdd(&deg[c], 1);
}

__global__ void k_dinv(const int* deg, float* dinv, int N) {
    int i = blockIdx.x * blockDim.x + threadIdx.x;
    if (i >= N) return;
    dinv[i] = rsqrtf((float)deg[i] + 1.0f);   // +1 = self-loop
}

// ---- exclusive scan over deg -> rowstart (3 kernels)
__global__ void k_blocksum(const int* deg, int* bsum, int N) {
    __shared__ int s[256];
    int i = blockIdx.x * 256 + threadIdx.x;
    s[threadIdx.x] = (i < N) ? deg[i] : 0;
    __syncthreads();
    for (int off = 128; off > 0; off >>= 1) {
        if (threadIdx.x < off) s[threadIdx.x] += s[threadIdx.x + off];
        __syncthreads();
    }
    if (threadIdx.x == 0) bsum[blockIdx.x] = s[0];
}

__global__ void k_scanbsum(int* bsum, int NB) {
    __shared__ int s[1024];
    __shared__ int carry_s;
    if (threadIdx.x == 0) carry_s = 0;
    __syncthreads();
    for (int base = 0; base < NB; base += 1024) {
        int i = base + threadIdx.x;
        int v = (i < NB) ? bsum[i] : 0;
        s[threadIdx.x] = v;
        __syncthreads();
        for (int off = 1; off < 1024; off <<= 1) {
            int t = (threadIdx.x >= off) ? s[threadIdx.x - off] : 0;
            __syncthreads();
            s[threadIdx.x] += t;
            __syncthreads();
        }
        int total = s[1023];
        int excl = s[threadIdx.x] - v + carry_s;
        if (i < NB) bsum[i] = excl;
        __syncthreads();
        if (threadIdx.x == 0) carry_s += total;
        __syncthreads();
    }
}

// rowstart + pre-seeded fill (saves a random load per edge in k_scatter)
__global__ void k_scanfinal(const int* deg, const int* boff, int* rowstart, int* fill, int N) {
    __shared__ int s[256];
    int i = blockIdx.x * 256 + threadIdx.x;
    int v = (i < N) ? deg[i] : 0;
    s[threadIdx.x] = v;
    __syncthreads();
    for (int off = 1; off < 256; off <<= 1) {
        int t = (threadIdx.x >= off) ? s[threadIdx.x - off] : 0;
        __syncthreads();
        s[threadIdx.x] += t;
        __syncthreads();
    }
    if (i < N) {
        int rs = boff[blockIdx.x] + s[threadIdx.x] - v;
        rowstart[i] = rs;
        fill[i] = rs;
    }
    if (i == N - 1) rowstart[N] = boff[blockIdx.x] + s[threadIdx.x];
}

// ---- bucket-scatter edges into CSR, XCD-sliced; r loaded ONLY for passing edges
__global__ void k_scatter(const int* ei, const int* flags, int* fill, int* erow,
                          int E, int N) {
    int slice = blockIdx.x & 7;
    int nlo = (int)(((long)N * slice) >> 3);
    int nhi = (int)(((long)N * (slice + 1)) >> 3);
    int nblk = gridDim.x >> 3;
    int bid = blockIdx.x >> 3;
    int i64 = flags[1];
    for (int e = bid * 256 + threadIdx.x; e < E; e += nblk * 256) {
        int c;
        if (i64) c = ei[2 * (E + e)];
        else     c = ei[E + e];
        if (c >= nlo && c < nhi) {
            int r;
            if (i64) r = ei[2 * e];
            else     r = ei[e];
            int pos = atomicAdd(&fill[c], 1);
            erow[pos] = r;
        }
    }
}

// ---- GEMM1 via MFMA (HW-verified in R0): h1b[n][c] = bf16(sum_k x[n][k]*W1[k][c])
//      A: lane l, elem j -> A[l&15][(l>>4)*8 + j]
//      B: lane l, elem j -> B[(l>>4)*8 + j][l&15]
//      C: lane l, reg  q -> C[(l>>4)*4 + q][l&15]
__global__ __launch_bounds__(256) void k_gemm1_mfma(const void* x, const float* W1f,
        __hip_bfloat16* h1b, const int* flags, int N) {
    __shared__ __align__(16) unsigned short wT[HID][IN_CH];   // W1^T, bf16 bits, 16 KB
    for (int i = threadIdx.x; i < IN_CH * HID; i += 256) {
        int k = i >> 6, c = i & 63;
        __hip_bfloat16 b = __float2bfloat16(W1f[i]);
        wT[c][k] = *reinterpret_cast<unsigned short*>(&b);
    }
    __syncthreads();

    const int isF32 = flags[0];
    const int lane = threadIdx.x & 63;
    const int wid  = threadIdx.x >> 6;
    const int r = lane & 15;     // A row / B col / C col within tile
    const int g = lane >> 4;     // k-group

    bf16x8 bfr[4][4];
    #pragma unroll
    for (int nt = 0; nt < 4; ++nt)
        #pragma unroll
        for (int ks = 0; ks < 4; ++ks)
            bfr[nt][ks] = *(const bf16x8*)&wT[nt * 16 + r][ks * 32 + g * 8];

    const int tiles = (N + 15) >> 4;
    for (int t = blockIdx.x * 4 + wid; t < tiles; t += gridDim.x * 4) {
        const int row0 = t * 16;
        int arow = row0 + r; if (arow >= N) arow = N - 1;   // clamp (stores guarded)
        bf16x8 afr[4];
        if (!isF32) {
            const unsigned short* xr = (const unsigned short*)x + (size_t)arow * IN_CH;
            #pragma unroll
            for (int ks = 0; ks < 4; ++ks)
                afr[ks] = *(const bf16x8*)&xr[ks * 32 + g * 8];
        } else {
            const float* xr = (const float*)x + (size_t)arow * IN_CH;
            #pragma unroll
            for (int ks = 0; ks < 4; ++ks) {
                #pragma unroll
                for (int j = 0; j < 8; ++j) {
                    __hip_bfloat16 b = __float2bfloat16(xr[ks * 32 + g * 8 + j]);
                    afr[ks][j] = *reinterpret_cast<short*>(&b);
                }
            }
        }
        f32x4 acc[4] = {};
        #pragma unroll
        for (int ks = 0; ks < 4; ++ks)
            #pragma unroll
            for (int nt = 0; nt < 4; ++nt)
                acc[nt] = __builtin_amdgcn_mfma_f32_16x16x32_bf16(afr[ks], bfr[nt][ks],
                                                                  acc[nt], 0, 0, 0);
        #pragma unroll
        for (int nt = 0; nt < 4; ++nt) {
            #pragma unroll
            for (int q = 0; q < 4; ++q) {
                int rr = row0 + g * 4 + q;
                if (rr < N)
                    h1b[(size_t)rr * HID + nt * 16 + r] = __float2bfloat16(acc[nt][q]);
            }
        }
    }
}

// ---- Pure aggregation 1: g[w] = relu(d^2*h1[w] + sum_e n*h1[r] + b1), bf16 out.
//      Persistent grid, no LDS, no barrier. lane=(sub,cq); 16 edges in flight.
__global__ __launch_bounds__(256) void k_agg1(const int* rowstart, const int* erow,
        const __hip_bfloat16* h1b, const float* dinv, const float* b1f,
        __hip_bfloat16* g, int N) {
    const int lane = threadIdx.x & 63;
    const int sub = lane >> 4;
    const int cq  = lane & 15;
    const f32x4 b1q = *(const f32x4*)&b1f[cq * 4];
    const int wstride = (gridDim.x * 256) >> 6;
    for (int w = (blockIdx.x * 256 + threadIdx.x) >> 6; w < N; w += wstride) {
        int s0 = __builtin_amdgcn_readfirstlane(rowstart[w]);
        int s1 = __builtin_amdgcn_readfirstlane(rowstart[w + 1]);
        float d = dinv[w];
        bf16x4 sv = *(const bf16x4*)&h1b[(size_t)w * HID + cq * 4];
        f32x4 acc = {0.f, 0.f, 0.f, 0.f};
        int i = s0 + sub;
        for (; i + 12 < s1; i += 16) {
            int r0 = erow[i], r1 = erow[i + 4], r2 = erow[i + 8], r3 = erow[i + 12];
            float n0 = dinv[r0] * d, n1 = dinv[r1] * d, n2 = dinv[r2] * d, n3 = dinv[r3] * d;
            f32x4 v0 = cvt4(*(const bf16x4*)&h1b[(size_t)r0 * HID + cq * 4]);
            f32x4 v1 = cvt4(*(const bf16x4*)&h1b[(size_t)r1 * HID + cq * 4]);
            f32x4 v2 = cvt4(*(const bf16x4*)&h1b[(size_t)r2 * HID + cq * 4]);
            f32x4 v3 = cvt4(*(const bf16x4*)&h1b[(size_t)r3 * HID + cq * 4]);
            #pragma unroll
            for (int j = 0; j < 4; ++j) {
                acc[j] = fmaf(v0[j], n0, acc[j]);
                acc[j] = fmaf(v1[j], n1, acc[j]);
                acc[j] = fmaf(v2[j], n2, acc[j]);
                acc[j] = fmaf(v3[j], n3, acc[j]);
            }
        }
        for (; i + 4 < s1; i += 8) {
            int r0 = erow[i], r1 = erow[i + 4];
            float n0 = dinv[r0] * d, n1 = dinv[r1] * d;
            f32x4 v0 = cvt4(*(const bf16x4*)&h1b[(size_t)r0 * HID + cq * 4]);
            f32x4 v1 = cvt4(*(const bf16x4*)&h1b[(size_t)r1 * HID + cq * 4]);
            #pragma unroll
            for (int j = 0; j < 4; ++j) {
                acc[j] = fmaf(v0[j], n0, acc[j]);
                acc[j] = fmaf(v1[j], n1, acc[j]);
            }
        }
        if (i < s1) {
            int r0 = erow[i];
            float n0 = dinv[r0] * d;
            f32x4 v0 = cvt4(*(const bf16x4*)&h1b[(size_t)r0 * HID + cq * 4]);
            #pragma unroll
            for (int j = 0; j < 4; ++j) acc[j] = fmaf(v0[j], n0, acc[j]);
        }
        #pragma unroll
        for (int j = 0; j < 4; ++j) {
            acc[j] += __shfl_xor(acc[j], 16);
            acc[j] += __shfl_xor(acc[j], 32);
        }
        if (sub == 0) {
            float dd = d * d;
            f32x4 sf = cvt4(sv);
            f32x4 gv;
            #pragma unroll
            for (int j = 0; j < 4; ++j)
                gv[j] = fmaxf(fmaf(sf[j], dd, acc[j]) + b1q[j], 0.f);
            *(bf16x4*)&g[(size_t)w * HID + cq * 4] = pack4(gv);
        }
    }
}

// ---- Pure aggregation 2: s[w] = d^2*g[w] + sum_e n*g[r], bf16 out (no bias/relu;
//      GEMM2 commutes past aggregation: out = agg(g) @ W2 + b2).
__global__ __launch_bounds__(256) void k_agg2s(const int* rowstart, const int* erow,
        const __hip_bfloat16* g, const float* dinv, __hip_bfloat16* sbuf, int N) {
    const int lane = threadIdx.x & 63;
    const int sub = lane >> 4;
    const int cq  = lane & 15;
    const int wstride = (gridDim.x * 256) >> 6;
    for (int w = (blockIdx.x * 256 + threadIdx.x) >> 6; w < N; w += wstride) {
        int s0 = __builtin_amdgcn_readfirstlane(rowstart[w]);
        int s1 = __builtin_amdgcn_readfirstlane(rowstart[w + 1]);
        float d = dinv[w];
        bf16x4 sv = *(const bf16x4*)&g[(size_t)w * HID + cq * 4];
        f32x4 acc = {0.f, 0.f, 0.f, 0.f};
        int i = s0 + sub;
        for (; i + 12 < s1; i += 16) {
            int r0 = erow[i], r1 = erow[i + 4], r2 = erow[i + 8], r3 = erow[i + 12];
            float n0 = dinv[r0] * d, n1 = dinv[r1] * d, n2 = dinv[r2] * d, n3 = dinv[r3] * d;
            f32x4 v0 = cvt4(*(const bf16x4*)&g[(size_t)r0 * HID + cq * 4]);
            f32x4 v1 = cvt4(*(const bf16x4*)&g[(size_t)r1 * HID + cq * 4]);
            f32x4 v2 = cvt4(*(const bf16x4*)&g[(size_t)r2 * HID + cq * 4]);
            f32x4 v3 = cvt4(*(const bf16x4*)&g[(size_t)r3 * HID + cq * 4]);
            #pragma unroll
            for (int j = 0; j < 4; ++j) {
                acc[j] = fmaf(v0[j], n0, acc[j]);
                acc[j] = fmaf(v1[j], n1, acc[j]);
                acc[j] = fmaf(v2[j], n2, acc[j]);
                acc[j] = fmaf(v3[j], n3, acc[j]);
            }
        }
        for (; i + 4 < s1; i += 8) {
            int r0 = erow[i], r1 = erow[i + 4];
            float n0 = dinv[r0] * d, n1 = dinv[r1] * d;
            f32x4 v0 = cvt4(*(const bf16x4*)&g[(size_t)r0 * HID + cq * 4]);
            f32x4 v1 = cvt4(*(const bf16x4*)&g[(size_t)r1 * HID + cq * 4]);
            #pragma unroll
            for (int j = 0; j < 4; ++j) {
                acc[j] = fmaf(v0[j], n0, acc[j]);
                acc[j] = fmaf(v1[j], n1, acc[j]);
            }
        }
        if (i < s1) {
            int r0 = erow[i];
            float n0 = dinv[r0] * d;
            f32x4 v0 = cvt4(*(const bf16x4*)&g[(size_t)r0 * HID + cq * 4]);
            #pragma unroll
            for (int j = 0; j < 4; ++j) acc[j] = fmaf(v0[j], n0, acc[j]);
        }
        #pragma unroll
        for (int j = 0; j < 4; ++j) {
            acc[j] += __shfl_xor(acc[j], 16);
            acc[j] += __shfl_xor(acc[j], 32);
        }
        if (sub == 0) {
            float dd = d * d;
            f32x4 sf = cvt4(sv);
            f32x4 ov;
            #pragma unroll
            for (int j = 0; j < 4; ++j) ov[j] = fmaf(sf[j], dd, acc[j]);
            *(bf16x4*)&sbuf[(size_t)w * HID + cq * 4] = pack4(ov);
        }
    }
}

// ---- GEMM2 via MFMA: out[n][c] = sum_k s[n][k]*W2[k][c] + b2[c], f32 out.
//      K=64 (2 k-slices), cols padded 40->48 (3 col-tiles). Same fragment layout
//      as gemm1 (HW-verified).
__global__ __launch_bounds__(256) void k_gemm2_mfma(const __hip_bfloat16* sbuf,
        const float* W2f, const float* b2f, float* out, int N) {
    __shared__ __align__(16) unsigned short w2T[48][HID];   // W2^T padded, bf16 bits, 6 KB
    for (int i = threadIdx.x; i < 48 * HID; i += 256) {
        int c = i >> 6, k = i & 63;
        float v = (c < OUT_CH) ? W2f[k * OUT_CH + c] : 0.f;
        __hip_bfloat16 b = __float2bfloat16(v);
        w2T[c][k] = *reinterpret_cast<unsigned short*>(&b);
    }
    __syncthreads();

    const int lane = threadIdx.x & 63;
    const int wid  = threadIdx.x >> 6;
    const int r = lane & 15;
    const int gq = lane >> 4;

    bf16x8 bfr[3][2];
    #pragma unroll
    for (int nt = 0; nt < 3; ++nt)
        #pragma unroll
        for (int ks = 0; ks < 2; ++ks)
            bfr[nt][ks] = *(const bf16x8*)&w2T[nt * 16 + r][ks * 32 + gq * 8];
    float b2v[3];
    #pragma unroll
    for (int nt = 0; nt < 3; ++nt)
        b2v[nt] = (nt * 16 + r < OUT_CH) ? b2f[nt * 16 + r] : 0.f;

    const int tiles = (N + 15) >> 4;
    for (int t = blockIdx.x * 4 + wid; t < tiles; t += gridDim.x * 4) {
        const int row0 = t * 16;
        int arow = row0 + r; if (arow >= N) arow = N - 1;
        const unsigned short* sr = (const unsigned short*)sbuf + (size_t)arow * HID;
        bf16x8 afr[2];
        afr[0] = *(const bf16x8*)&sr[gq * 8];
        afr[1] = *(const bf16x8*)&sr[32 + gq * 8];
        f32x4 acc[3] = {};
        #pragma unroll
        for (int ks = 0; ks < 2; ++ks)
            #pragma unroll
            for (int nt = 0; nt < 3; ++nt)
                acc[nt] = __builtin_amdgcn_mfma_f32_16x16x32_bf16(afr[ks], bfr[nt][ks],
                                                                  acc[nt], 0, 0, 0);
        #pragma unroll
        for (int nt = 0; nt < 3; ++nt) {
            int c = nt * 16 + r;
            #pragma unroll
            for (int q = 0; q < 4; ++q) {
                int rr = row0 + gq * 4 + q;
                if (rr < N && c < OUT_CH)
                    out[(size_t)rr * OUT_CH + c] = acc[nt][q] + b2v[nt];
            }
        }
    }
}

extern "C" void kernel_launch(void* const* d_in, const int* in_sizes, int n_in,
                              void* d_out, int out_size, void* d_ws, size_t ws_size,
                              hipStream_t stream) {
    const void* x  = d_in[0];
    const void* ei = d_in[1];
    const void* W1 = d_in[2];
    const void* b1 = d_in[3];
    const void* W2 = d_in[4];
    const void* b2 = d_in[5];
    const int N = in_sizes[0] / IN_CH;   // 100000
    const int E = in_sizes[1] / 2;       // 1600000
    const int* eii = (const int*)ei;
    const int NB = (N + 255) / 256;

    // ---- workspace layout (4-byte units). Peak ~35 MiB (s aliases h1b).
    float* ws = (float*)d_ws;
    size_t off = 16;
    int*   flags    = (int*)ws;
    int*   deg      = (int*)ws + off;            off += N;
    int*   fill     = (int*)ws + off;            off += N;
    float* dinv     = ws + off;                  off += N;
    float* wf       = ws + off;                  off += 10880;
    int*   bsum     = (int*)ws + off;            off += NB + 16;
    int*   rowstart = (int*)ws + off;            off += N + 1;
    off = (off + 255) & ~(size_t)255;
    int*   erow     = (int*)ws + off;            off += E;
    __hip_bfloat16* h1b = (__hip_bfloat16*)(ws + off);     off += (size_t)N * HID / 2;
    __hip_bfloat16* g   = (__hip_bfloat16*)(ws + off);     off += (size_t)N * HID / 2;
    __hip_bfloat16* sbuf = h1b;   // h1b is dead once k_agg1 completes

    hipMemsetAsync(deg, 0, (size_t)N * sizeof(int), stream);  // deg only; fill pre-seeded

    k_detect<<<1, 256, 0, stream>>>(x, ei, flags);
    k_convw<<<(10856 + 255) / 256, 256, 0, stream>>>(W1, b1, W2, b2, flags, wf);
    k_deg<<<(E + 255) / 256, 256, 0, stream>>>(eii, flags, deg, E);
    k_dinv<<<(N + 255) / 256, 256, 0, stream>>>(deg, dinv, N);

    k_blocksum<<<NB, 256, 0, stream>>>(deg, bsum, N);
    k_scanbsum<<<1, 1024, 0, stream>>>(bsum, NB);
    k_scanfinal<<<NB, 256, 0, stream>>>(deg, bsum, rowstart, fill, N);
    k_scatter<<<4096, 256, 0, stream>>>(eii, flags, fill, erow, E, N);

    int tiles = (N + 15) / 16;
    int g1 = (tiles + 7) / 8;           // 4 waves/block, 2 tiles/wave
    k_gemm1_mfma<<<g1, 256, 0, stream>>>(x, wf, h1b, flags, N);

    k_agg1<<<2048, 256, 0, stream>>>(rowstart, erow, h1b, dinv, wf + 8192, g, N);
    k_agg2s<<<2048, 256, 0, stream>>>(rowstart, erow, g, dinv, sbuf, N);
    k_gemm2_mfma<<<g1, 256, 0, stream>>>(sbuf, wf + 8256, wf + 10816, (float*)d_out, N);
}